// Round 4
// baseline (460.406 us; speedup 1.0000x reference)
//
#include <hip/hip_runtime.h>
#include <hip/hip_bf16.h>

// ---------------------------------------------------------------------------
// RETAIN forward, MI355X gfx950.
// T=64, B=64, D_IN=4096, E=128, HA=HB=128, D_OUT=4096
// R4: k_recur — W_hh B-fragments pinned in AGPRs (asm "+a"), conflict-free
//     fragment-order W_beta LDS tile, alpha via DPP shfl reduction (no MFMA),
//     gi3 packed layout {6 gates, emb, pad} -> 8 VMEM/step, b_hh r/z folded
//     into gi3 at producer, decrementing row pointers.
// ---------------------------------------------------------------------------

typedef __attribute__((ext_vector_type(8))) short short8;
typedef __attribute__((ext_vector_type(4))) float f32x4;

#define MFMA16(a, b, c) __builtin_amdgcn_mfma_f32_16x16x32_bf16((a), (b), (c), 0, 0, 0)

__device__ __forceinline__ unsigned short f2bf(float f) {
  unsigned int u = __float_as_uint(f);
  u += 0x7fffu + ((u >> 16) & 1u);   // RNE (inputs are never NaN here)
  return (unsigned short)(u >> 16);
}
__device__ __forceinline__ unsigned pkbf(float a, float b) {  // v_cvt_pk_bf16_f32
  __hip_bfloat162 t = __float22bfloat162_rn(float2{a, b});
  return *reinterpret_cast<unsigned*>(&t);
}
__device__ __forceinline__ float sigm(float x) { return 1.0f / (1.0f + __expf(-x)); }
__device__ __forceinline__ float tanh_f(float x) {
  // one-sided clamp: e overflows only for x < -44 (tanh == -1 there)
  float e = __expf(-2.0f * fmaxf(x, -44.0f));
  return (1.0f - e) / (1.0f + e);
}

// ---- workspace layout (byte offsets), total ~36.4 MiB ----
#define OFF_PART   0u           // 8 * 524288 f32        emb K-split partials
#define OFF_GI3    16777216u    // 4096*1024 f32         per (j,b,kout): {ra,za,na,rb,zb,nb,emb,pad}
#define OFF_EMBBF  33554432u    // 524288 bf16
#define OFF_CBF    34603008u    // 524288 bf16           c (T*B, 128)
#define OFF_WEMB   35651584u    // 524288 bf16
#define OFF_WOUT   36700160u    // 524288 bf16
#define OFF_WHHA   37748736u    // 49152 bf16
#define OFF_WHHB   37847040u    // 49152 bf16
#define OFF_WIH    37945344u    // 98304 bf16            [W_ih_a ; W_ih_b]
#define OFF_WBETA  38141952u    // 16384 bf16            0.5 * W_beta

// ---------------------------------------------------------------------------
// pair-wise weight cast (all section boundaries are even)
__global__ void k_prep(const float* W_emb, const float* W_out,
                       const float* W_hh_a, const float* W_hh_b,
                       const float* W_ih_a, const float* W_ih_b,
                       const float* W_beta,
                       unsigned* wemb, unsigned* wout,
                       unsigned* whha, unsigned* whhb,
                       unsigned* wih, unsigned* wbeta) {
  const unsigned total = 630784u;  // element-pairs
  for (unsigned idx = blockIdx.x * 256u + threadIdx.x; idx < total;
       idx += gridDim.x * 256u) {
    unsigned i = idx;
    if (i < 262144u) { float2 v = ((const float2*)W_emb)[i]; wemb[i] = pkbf(v.x, v.y); continue; }
    i -= 262144u;
    if (i < 262144u) { float2 v = ((const float2*)W_out)[i]; wout[i] = pkbf(v.x, v.y); continue; }
    i -= 262144u;
    if (i < 24576u) { float2 v = ((const float2*)W_hh_a)[i]; whha[i] = pkbf(v.x, v.y); continue; }
    i -= 24576u;
    if (i < 24576u) { float2 v = ((const float2*)W_hh_b)[i]; whhb[i] = pkbf(v.x, v.y); continue; }
    i -= 24576u;
    if (i < 24576u) { float2 v = ((const float2*)W_ih_a)[i]; wih[i] = pkbf(v.x, v.y); continue; }
    i -= 24576u;
    if (i < 24576u) { float2 v = ((const float2*)W_ih_b)[i]; wih[24576u + i] = pkbf(v.x, v.y); continue; }
    i -= 24576u;
    { float2 v = ((const float2*)W_beta)[i]; wbeta[i] = pkbf(0.5f * v.x, 0.5f * v.y); }
  }
}

// ---------------------------------------------------------------------------
// emb partials: 256 blocks = 32 m-tiles(128) x 8 K-chunks(512). N = 128 (full E).
__global__ __launch_bounds__(256) void k_emb_gemm(const float* __restrict__ x,
                                                  const unsigned short* __restrict__ wemb,
                                                  float* __restrict__ part) {
  const int mt = blockIdx.x >> 3, kc = blockIdx.x & 7;
  const int w = threadIdx.x >> 6, lane = threadIdx.x & 63, q = lane >> 4, ln = lane & 15;
  const f32x4 zero = {0.f, 0.f, 0.f, 0.f};
  f32x4 acc[2][8];
#pragma unroll
  for (int a = 0; a < 2; ++a)
#pragma unroll
    for (int b = 0; b < 8; ++b) acc[a][b] = zero;

  const float* xA = x + (size_t)(mt * 128 + (2 * w) * 16 + ln) * 4096 + kc * 512 + q * 8;
  const float* xB = xA + (size_t)16 * 4096;

  for (int kk = 0; kk < 16; ++kk) {
    const int ko = kk * 32;
    float4 u0 = *(const float4*)(xA + ko);
    float4 u1 = *(const float4*)(xA + ko + 4);
    float4 v0 = *(const float4*)(xB + ko);
    float4 v1 = *(const float4*)(xB + ko + 4);
    union { short8 v; unsigned u[4]; } a0, a1;
    a0.u[0] = pkbf(u0.x, u0.y); a0.u[1] = pkbf(u0.z, u0.w);
    a0.u[2] = pkbf(u1.x, u1.y); a0.u[3] = pkbf(u1.z, u1.w);
    a1.u[0] = pkbf(v0.x, v0.y); a1.u[1] = pkbf(v0.z, v0.w);
    a1.u[2] = pkbf(v1.x, v1.y); a1.u[3] = pkbf(v1.z, v1.w);
#pragma unroll
    for (int nt = 0; nt < 8; ++nt) {
      short8 b = *(const short8*)(wemb + (size_t)(nt * 16 + ln) * 4096 + kc * 512 + ko + q * 8);
      acc[0][nt] = MFMA16(a0.v, b, acc[0][nt]);
      acc[1][nt] = MFMA16(a1.v, b, acc[1][nt]);
    }
  }
#pragma unroll
  for (int st = 0; st < 2; ++st) {
    const int mbase = mt * 128 + (2 * w + st) * 16 + q * 4;
#pragma unroll
    for (int nt = 0; nt < 8; ++nt)
#pragma unroll
      for (int r = 0; r < 4; ++r)
        part[(size_t)kc * 524288 + (size_t)(mbase + r) * 128 + nt * 16 + ln] = acc[st][nt][r];
  }
}

// ---------------------------------------------------------------------------
// reduce K-split partials; write gi3 slot 6 (emb f32) + embbf (bf16 pairs)
__global__ void k_emb_reduce(const float* __restrict__ part, const float* __restrict__ b_emb,
                             float* __restrict__ gi3, unsigned* __restrict__ embbf) {
  const unsigned pidx = blockIdx.x * 256u + threadIdx.x;  // < 262144 pairs
  const unsigned e0 = (pidx * 2u) & 127u;
  const unsigned m = pidx >> 6;  // row (t*64+b)
  float2 s = ((const float2*)b_emb)[e0 >> 1];
#pragma unroll
  for (int kc = 0; kc < 8; ++kc) {
    float2 v = ((const float2*)(part + (size_t)kc * 524288u))[pidx];
    s.x += v.x; s.y += v.y;
  }
  gi3[(size_t)m * 1024u + e0 * 8u + 6u] = s.x;
  gi3[(size_t)m * 1024u + (e0 + 1u) * 8u + 6u] = s.y;
  embbf[pidx] = pkbf(s.x, s.y);
}

// ---------------------------------------------------------------------------
// gi3 gates: M=4096, N=768. col g: gate gg=g>>7 (0..2: GRU-a r,z,n; 3..5: b),
// kout=g&127 -> gi3[row*1024 + kout*8 + gg]. b_ih always folded; b_hh folded
// for r,z gates only (n-gate's hidden bias is multiplied by r downstream).
__global__ __launch_bounds__(256) void k_gi_gemm(const unsigned short* __restrict__ embbf,
                                                 const unsigned short* __restrict__ wih,
                                                 const float* __restrict__ b_ih_a,
                                                 const float* __restrict__ b_ih_b,
                                                 const float* __restrict__ b_hh_a,
                                                 const float* __restrict__ b_hh_b,
                                                 float* __restrict__ gi3) {
  const int mt = blockIdx.x / 6, nt6 = blockIdx.x % 6, nbase = nt6 * 128;
  const int w = threadIdx.x >> 6, lane = threadIdx.x & 63, q = lane >> 4, ln = lane & 15;
  const f32x4 zero = {0.f, 0.f, 0.f, 0.f};
  f32x4 acc[2][8];
#pragma unroll
  for (int a = 0; a < 2; ++a)
#pragma unroll
    for (int b = 0; b < 8; ++b) acc[a][b] = zero;

#pragma unroll
  for (int kk = 0; kk < 4; ++kk) {
    const int ko = kk * 32 + q * 8;
    short8 a0 = *(const short8*)(embbf + (size_t)(mt * 128 + (2 * w) * 16 + ln) * 128 + ko);
    short8 a1 = *(const short8*)(embbf + (size_t)(mt * 128 + (2 * w + 1) * 16 + ln) * 128 + ko);
#pragma unroll
    for (int nt = 0; nt < 8; ++nt) {
      short8 b = *(const short8*)(wih + (size_t)(nbase + nt * 16 + ln) * 128 + ko);
      acc[0][nt] = MFMA16(a0, b, acc[0][nt]);
      acc[1][nt] = MFMA16(a1, b, acc[1][nt]);
    }
  }
#pragma unroll
  for (int nt = 0; nt < 8; ++nt) {
    const int g = nbase + nt * 16 + ln;
    const int gg = g >> 7, kout = g & 127;
    float bias;
    if (g < 384) bias = b_ih_a[g] + ((gg < 2) ? b_hh_a[g] : 0.0f);
    else {
      const int g2 = g - 384;
      bias = b_ih_b[g2] + ((gg < 5) ? b_hh_b[g2] : 0.0f);
    }
#pragma unroll
    for (int st = 0; st < 2; ++st) {
      const int mbase = mt * 128 + (2 * w + st) * 16 + q * 4;
#pragma unroll
      for (int r = 0; r < 4; ++r)
        gi3[(size_t)(mbase + r) * 1024 + kout * 8 + gg] = acc[st][nt][r] + bias;
    }
  }
}

// ---------------------------------------------------------------------------
// Fused recurrence + attention. 256 blocks x 512 threads, 1 block/CU.
// W_hh B-fragments pinned in AGPRs via asm "+a" (96 AGPRs) — architecturally
// resident, immune to the scheduler's pressure heuristics. One barrier/step.
__global__ __launch_bounds__(512) __attribute__((amdgpu_waves_per_eu(2, 2)))
void k_recur(const float* __restrict__ gi3,
             const unsigned short* __restrict__ whha, const unsigned short* __restrict__ whhb,
             const unsigned short* __restrict__ wbeta,
             const float* __restrict__ b_hh_a, const float* __restrict__ b_hh_b,
             const float* __restrict__ b_beta, const float* __restrict__ b_alpha,
             const float* __restrict__ w_alpha,
             unsigned short* __restrict__ cbf) {
  const int tid = threadIdx.x, w = tid >> 6, lane = tid & 63, q = lane >> 4, ln = lane & 15;
  const int p = blockIdx.x >> 3, btile = blockIdx.x & 7;
  const int i1 = p, i2 = 63 - p;  // i2 >= i1
  const int kout = w * 16 + ln;

  // h double-buffered, rows padded to 136 shorts (balanced 8-way b128 reads).
  // wbeta_s in FRAGMENT order: lane-contiguous 16B chunks (R3's row-major tile
  // was a 16-way conflict). ap: cross-wave alpha partials, double-buffered.
  __shared__ unsigned short hA[2][16 * 136], hB[2][16 * 136];
  __shared__ unsigned short wbeta_s[16384];
  __shared__ __align__(16) float ap[2][16][8];

  for (int idx = tid; idx < 16 * 136; idx += 512) { hA[0][idx] = 0; hB[0][idx] = 0; }
  for (int c = tid; c < 2048; c += 512) {
    const int cw = c >> 8, ckc = (c >> 6) & 3, cq = (c >> 4) & 3, cl = c & 15;
    *(short8*)(wbeta_s + c * 8) =
        *(const short8*)(wbeta + (size_t)(cw * 16 + cl) * 128 + ckc * 32 + cq * 8);
  }

  const int iq = (q < 2) ? i1 : i2;     // query index for this lane's 4 rows
  // gate-input row pointers (decremented per step; all 4 r share one j)
  const float* gp[4];
#pragma unroll
  for (int r = 0; r < 4; ++r) {
    const int b = btile * 8 + (q & 1) * 4 + r;
    gp[r] = gi3 + (size_t)(iq * 64 + b) * 1024 + kout * 8;
  }

  // ---- W_hh B-fragments -> AGPRs (96 regs, pinned)
  short8 fra[3][4], frb[3][4];
#pragma unroll
  for (int g = 0; g < 3; ++g) {
    const unsigned short* ba = whha + (size_t)(g * 128 + kout) * 128;
    const unsigned short* bb = whhb + (size_t)(g * 128 + kout) * 128;
#pragma unroll
    for (int kc = 0; kc < 4; ++kc) {
      fra[g][kc] = *(const short8*)(ba + kc * 32 + q * 8);
      frb[g][kc] = *(const short8*)(bb + kc * 32 + q * 8);
    }
  }
#pragma unroll
  for (int g = 0; g < 3; ++g)
#pragma unroll
    for (int kc = 0; kc < 4; ++kc) {
      asm volatile("" : "+a"(fra[g][kc]));
      asm volatile("" : "+a"(frb[g][kc]));
    }

  const float bhnA = b_hh_a[256 + kout];   // n-gate hidden biases (not foldable)
  const float bhnB = b_hh_b[256 + kout];
  const float bbet = b_beta[kout];
  const float bal = b_alpha[0];
  const float wa = 0.5f * w_alpha[kout];

  float hRA[4], hRB[4], cac[4], lreg[4];
#pragma unroll
  for (int r = 0; r < 4; ++r) { hRA[r] = 0.f; hRB[r] = 0.f; cac[r] = 0.f; lreg[r] = 0.f; }

  const f32x4 zero = {0.f, 0.f, 0.f, 0.f};
  int jj = iq;
  __syncthreads();

  for (int s = 0; s <= i2; ++s) {
    const int rb = s & 1, wb = rb ^ 1;

    // ---- step-top VMEM: 2 x float4 per r = {ra,za,na,rb | zb,nb,emb,pad}
    float4 lo[4], hi[4];
#pragma unroll
    for (int r = 0; r < 4; ++r) { lo[r] = *(const float4*)gp[r]; hi[r] = *(const float4*)(gp[r] + 4); }

    // ---- h_old A-fragments
    short8 haf[4], hbf[4];
#pragma unroll
    for (int kc = 0; kc < 4; ++kc) {
      haf[kc] = *(const short8*)(hA[rb] + ln * 136 + kc * 32 + q * 8);
      hbf[kc] = *(const short8*)(hB[rb] + ln * 136 + kc * 32 + q * 8);
    }

    // ---- gate MFMAs (24/wave, B from AGPR)
    f32x4 accA[3] = {zero, zero, zero}, accB[3] = {zero, zero, zero};
#pragma unroll
    for (int kc = 0; kc < 4; ++kc)
#pragma unroll
      for (int g = 0; g < 3; ++g) {
        accA[g] = MFMA16(haf[kc], fra[g][kc], accA[g]);
        accB[g] = MFMA16(hbf[kc], frb[g][kc], accB[g]);
      }

    // ---- gate math, h_new -> LDS, alpha partial via DPP reduction
#pragma unroll
    for (int r = 0; r < 4; ++r) {
      const int rowoff = (q * 4 + r) * 136 + kout;
      const float rrA = sigm(lo[r].x + accA[0][r]);
      const float zzA = sigm(lo[r].y + accA[1][r]);
      const float nnA = tanh_f(lo[r].z + rrA * (accA[2][r] + bhnA));
      const float hnA = (1.f - zzA) * nnA + zzA * hRA[r];
      hRA[r] = hnA;
      hA[wb][rowoff] = f2bf(hnA);

      const float rrB = sigm(lo[r].w + accB[0][r]);
      const float zzB = sigm(hi[r].x + accB[1][r]);
      const float nnB = tanh_f(hi[r].y + rrB * (accB[2][r] + bhnB));
      const float hnB = (1.f - zzB) * nnB + zzB * hRB[r];
      hRB[r] = hnB;
      hB[wb][rowoff] = f2bf(hnB);

      float av = hnA * wa;               // this wave's 16-col partial of logit
      av += __shfl_xor(av, 1); av += __shfl_xor(av, 2);
      av += __shfl_xor(av, 4); av += __shfl_xor(av, 8);
      if (ln == 0) ap[wb][q * 4 + r][w] = av;
    }
    __syncthreads();  // the ONLY barrier per step

    // ---- phase B: beta MFMA on h_new + logit assembly
    short8 hnBf[4], fbe[4];
#pragma unroll
    for (int kc = 0; kc < 4; ++kc) {
      hnBf[kc] = *(const short8*)(hB[wb] + ln * 136 + kc * 32 + q * 8);
      fbe[kc] = *(const short8*)(wbeta_s + (size_t)(((w * 4 + kc) * 4 + q) * 16 + ln) * 8);
    }
    f32x4 accV = zero;
#pragma unroll
    for (int kc = 0; kc < 4; ++kc) accV = MFMA16(hnBf[kc], fbe[kc], accV);

    const bool act = (s <= iq);
#pragma unroll
    for (int r = 0; r < 4; ++r) {
      const float4* app = (const float4*)ap[wb][q * 4 + r];
      const float4 s0 = app[0], s1 = app[1];
      const float logit = s0.x + s0.y + s0.z + s0.w + s1.x + s1.y + s1.z + s1.w + bal;
      const float pp = act ? __expf(logit) : 0.0f;
      lreg[r] += pp;
      const float beta = tanh_f(accV[r] + bbet);
      cac[r] += pp * beta * hi[r].z;     // hi[r].z = emb value
    }

    // ---- advance row pointers (j decrements, clamped at 0)
    if (jj > 0) {
      --jj;
#pragma unroll
      for (int r = 0; r < 4; ++r) gp[r] -= 65536;  // 64 rows * 1024 floats
    }
  }

  // ---- epilogue
#pragma unroll
  for (int r = 0; r < 4; ++r) {
    const int b = btile * 8 + (q & 1) * 4 + r;
    const float val = cac[r] / (lreg[r] * (float)(iq + 1));
    cbf[(size_t)(iq * 64 + b) * 128 + kout] = f2bf(val);
  }
}

// ---------------------------------------------------------------------------
// out = sigmoid(c @ W_out.T + b_out): M=4096, N=4096, K=128. 1024 blocks of 128x128.
__global__ __launch_bounds__(256) void k_out_gemm(const unsigned short* __restrict__ cbf,
                                                  const unsigned short* __restrict__ wout,
                                                  const float* __restrict__ b_out,
                                                  float* __restrict__ out) {
  const int mt = blockIdx.x >> 5, nt32 = blockIdx.x & 31, nbase = nt32 * 128;
  const int w = threadIdx.x >> 6, lane = threadIdx.x & 63, q = lane >> 4, ln = lane & 15;
  const f32x4 zero = {0.f, 0.f, 0.f, 0.f};
  f32x4 acc[2][8];
#pragma unroll
  for (int a = 0; a < 2; ++a)
#pragma unroll
    for (int b = 0; b < 8; ++b) acc[a][b] = zero;

#pragma unroll
  for (int kk = 0; kk < 4; ++kk) {
    const int ko = kk * 32 + q * 8;
    short8 a0 = *(const short8*)(cbf + (size_t)(mt * 128 + (2 * w) * 16 + ln) * 128 + ko);
    short8 a1 = *(const short8*)(cbf + (size_t)(mt * 128 + (2 * w + 1) * 16 + ln) * 128 + ko);
#pragma unroll
    for (int nt = 0; nt < 8; ++nt) {
      short8 b = *(const short8*)(wout + (size_t)(nbase + nt * 16 + ln) * 128 + ko);
      acc[0][nt] = MFMA16(a0, b, acc[0][nt]);
      acc[1][nt] = MFMA16(a1, b, acc[1][nt]);
    }
  }
#pragma unroll
  for (int nt = 0; nt < 8; ++nt) {
    const int n = nbase + nt * 16 + ln;
    const float bo = b_out[n];
#pragma unroll
    for (int st = 0; st < 2; ++st) {
      const int mbase = mt * 128 + (2 * w + st) * 16 + q * 4;
#pragma unroll
      for (int r = 0; r < 4; ++r)
        out[(size_t)(mbase + r) * 4096 + n] = sigm(acc[st][nt][r] + bo);
    }
  }
}

// ---------------------------------------------------------------------------
extern "C" void kernel_launch(void* const* d_in, const int* in_sizes, int n_in,
                              void* d_out, int out_size, void* d_ws, size_t ws_size,
                              hipStream_t stream) {
  const float* x      = (const float*)d_in[0];
  const float* W_emb  = (const float*)d_in[1];
  const float* b_emb  = (const float*)d_in[2];
  const float* W_ih_a = (const float*)d_in[3];
  const float* W_hh_a = (const float*)d_in[4];
  const float* b_ih_a = (const float*)d_in[5];
  const float* b_hh_a = (const float*)d_in[6];
  const float* W_ih_b = (const float*)d_in[7];
  const float* W_hh_b = (const float*)d_in[8];
  const float* b_ih_b = (const float*)d_in[9];
  const float* b_hh_b = (const float*)d_in[10];
  const float* w_alpha = (const float*)d_in[11];
  const float* b_alpha = (const float*)d_in[12];
  const float* W_beta = (const float*)d_in[13];
  const float* b_beta = (const float*)d_in[14];
  const float* W_out  = (const float*)d_in[15];
  const float* b_out  = (const float*)d_in[16];
  float* out = (float*)d_out;

  char* ws = (char*)d_ws;
  float*          part   = (float*)(ws + OFF_PART);
  float*          gi3    = (float*)(ws + OFF_GI3);
  unsigned*       embbf  = (unsigned*)(ws + OFF_EMBBF);
  unsigned short* cbf    = (unsigned short*)(ws + OFF_CBF);
  unsigned*       wemb   = (unsigned*)(ws + OFF_WEMB);
  unsigned*       wout   = (unsigned*)(ws + OFF_WOUT);
  unsigned*       whha   = (unsigned*)(ws + OFF_WHHA);
  unsigned*       whhb   = (unsigned*)(ws + OFF_WHHB);
  unsigned*       wih    = (unsigned*)(ws + OFF_WIH);
  unsigned*       wbeta  = (unsigned*)(ws + OFF_WBETA);

  k_prep<<<1024, 256, 0, stream>>>(W_emb, W_out, W_hh_a, W_hh_b, W_ih_a, W_ih_b,
                                   W_beta, wemb, wout, whha, whhb, wih, wbeta);
  k_emb_gemm<<<256, 256, 0, stream>>>(x, (const unsigned short*)wemb, part);
  k_emb_reduce<<<1024, 256, 0, stream>>>(part, b_emb, gi3, embbf);
  k_gi_gemm<<<192, 256, 0, stream>>>((const unsigned short*)embbf, (const unsigned short*)wih,
                                     b_ih_a, b_ih_b, b_hh_a, b_hh_b, gi3);
  k_recur<<<256, 512, 0, stream>>>(gi3, (const unsigned short*)whha,
                                   (const unsigned short*)whhb, (const unsigned short*)wbeta,
                                   b_hh_a, b_hh_b, b_beta, b_alpha, w_alpha, cbf);
  k_out_gemm<<<1024, 256, 0, stream>>>(cbf, (const unsigned short*)wout, b_out, out);
}

// Round 5
// 415.649 us; speedup vs baseline: 1.1077x; 1.1077x over previous
//
#include <hip/hip_runtime.h>
#include <hip/hip_bf16.h>

// ---------------------------------------------------------------------------
// RETAIN forward, MI355X gfx950.
// T=64, B=64, D_IN=4096, E=128, HA=HB=128, D_OUT=4096
// R5: k_recur — deferred-attention restructure: h frags read ONCE/step and
//     feed gates + beta + alpha (alpha = 4 MFMAs w/ col0-only B-frag, AGPR);
//     raw s_barrier (lgkmcnt-only drain) + cross-barrier gi prefetch;
//     gi rows packed as 8 x fp16 (one 16B load). No ap/swizzle machinery.
// ---------------------------------------------------------------------------

typedef __attribute__((ext_vector_type(8))) short short8;
typedef __attribute__((ext_vector_type(4))) float f32x4;
typedef _Float16 half8 __attribute__((ext_vector_type(8)));

#define MFMA16(a, b, c) __builtin_amdgcn_mfma_f32_16x16x32_bf16((a), (b), (c), 0, 0, 0)

__device__ __forceinline__ unsigned short f2bf(float f) {
  unsigned int u = __float_as_uint(f);
  u += 0x7fffu + ((u >> 16) & 1u);   // RNE (inputs are never NaN here)
  return (unsigned short)(u >> 16);
}
__device__ __forceinline__ unsigned pkbf(float a, float b) {  // v_cvt_pk_bf16_f32
  __hip_bfloat162 t = __float22bfloat162_rn(float2{a, b});
  return *reinterpret_cast<unsigned*>(&t);
}
__device__ __forceinline__ float sigm(float x) { return 1.0f / (1.0f + __expf(-x)); }
__device__ __forceinline__ float tanh_f(float x) {
  // one-sided clamp: e overflows only for x < -44 (tanh == -1 there)
  float e = __expf(-2.0f * fmaxf(x, -44.0f));
  return (1.0f - e) / (1.0f + e);
}

// ---- workspace layout (byte offsets), total ~28.4 MiB ----
#define OFF_PART   0u           // 8 * 524288 f32   emb K-split partials
#define OFF_GI3    16777216u    // 4096*1024 fp16   per (j,b,kout): {ra,za,na,rb,zb,nb,emb,pad}
#define OFF_EMBBF  25165824u    // 524288 bf16
#define OFF_CBF    26214400u    // 524288 bf16      c (T*B, 128)
#define OFF_WEMB   27262976u    // 524288 bf16
#define OFF_WOUT   28311552u    // 524288 bf16
#define OFF_WHHA   29360128u    // 49152 bf16
#define OFF_WHHB   29458432u    // 49152 bf16
#define OFF_WIH    29556736u    // 98304 bf16       [W_ih_a ; W_ih_b]
#define OFF_WBETA  29753344u    // 16384 bf16       0.5 * W_beta

// ---------------------------------------------------------------------------
// pair-wise weight cast (all section boundaries are even)
__global__ void k_prep(const float* W_emb, const float* W_out,
                       const float* W_hh_a, const float* W_hh_b,
                       const float* W_ih_a, const float* W_ih_b,
                       const float* W_beta,
                       unsigned* wemb, unsigned* wout,
                       unsigned* whha, unsigned* whhb,
                       unsigned* wih, unsigned* wbeta) {
  const unsigned total = 630784u;  // element-pairs
  for (unsigned idx = blockIdx.x * 256u + threadIdx.x; idx < total;
       idx += gridDim.x * 256u) {
    unsigned i = idx;
    if (i < 262144u) { float2 v = ((const float2*)W_emb)[i]; wemb[i] = pkbf(v.x, v.y); continue; }
    i -= 262144u;
    if (i < 262144u) { float2 v = ((const float2*)W_out)[i]; wout[i] = pkbf(v.x, v.y); continue; }
    i -= 262144u;
    if (i < 24576u) { float2 v = ((const float2*)W_hh_a)[i]; whha[i] = pkbf(v.x, v.y); continue; }
    i -= 24576u;
    if (i < 24576u) { float2 v = ((const float2*)W_hh_b)[i]; whhb[i] = pkbf(v.x, v.y); continue; }
    i -= 24576u;
    if (i < 24576u) { float2 v = ((const float2*)W_ih_a)[i]; wih[i] = pkbf(v.x, v.y); continue; }
    i -= 24576u;
    if (i < 24576u) { float2 v = ((const float2*)W_ih_b)[i]; wih[24576u + i] = pkbf(v.x, v.y); continue; }
    i -= 24576u;
    { float2 v = ((const float2*)W_beta)[i]; wbeta[i] = pkbf(0.5f * v.x, 0.5f * v.y); }
  }
}

// ---------------------------------------------------------------------------
// emb partials: 256 blocks = 32 m-tiles(128) x 8 K-chunks(512). N = 128 (full E).
__global__ __launch_bounds__(256) void k_emb_gemm(const float* __restrict__ x,
                                                  const unsigned short* __restrict__ wemb,
                                                  float* __restrict__ part) {
  const int mt = blockIdx.x >> 3, kc = blockIdx.x & 7;
  const int w = threadIdx.x >> 6, lane = threadIdx.x & 63, q = lane >> 4, ln = lane & 15;
  const f32x4 zero = {0.f, 0.f, 0.f, 0.f};
  f32x4 acc[2][8];
#pragma unroll
  for (int a = 0; a < 2; ++a)
#pragma unroll
    for (int b = 0; b < 8; ++b) acc[a][b] = zero;

  const float* xA = x + (size_t)(mt * 128 + (2 * w) * 16 + ln) * 4096 + kc * 512 + q * 8;
  const float* xB = xA + (size_t)16 * 4096;

  for (int kk = 0; kk < 16; ++kk) {
    const int ko = kk * 32;
    float4 u0 = *(const float4*)(xA + ko);
    float4 u1 = *(const float4*)(xA + ko + 4);
    float4 v0 = *(const float4*)(xB + ko);
    float4 v1 = *(const float4*)(xB + ko + 4);
    union { short8 v; unsigned u[4]; } a0, a1;
    a0.u[0] = pkbf(u0.x, u0.y); a0.u[1] = pkbf(u0.z, u0.w);
    a0.u[2] = pkbf(u1.x, u1.y); a0.u[3] = pkbf(u1.z, u1.w);
    a1.u[0] = pkbf(v0.x, v0.y); a1.u[1] = pkbf(v0.z, v0.w);
    a1.u[2] = pkbf(v1.x, v1.y); a1.u[3] = pkbf(v1.z, v1.w);
#pragma unroll
    for (int nt = 0; nt < 8; ++nt) {
      short8 b = *(const short8*)(wemb + (size_t)(nt * 16 + ln) * 4096 + kc * 512 + ko + q * 8);
      acc[0][nt] = MFMA16(a0.v, b, acc[0][nt]);
      acc[1][nt] = MFMA16(a1.v, b, acc[1][nt]);
    }
  }
#pragma unroll
  for (int st = 0; st < 2; ++st) {
    const int mbase = mt * 128 + (2 * w + st) * 16 + q * 4;
#pragma unroll
    for (int nt = 0; nt < 8; ++nt)
#pragma unroll
      for (int r = 0; r < 4; ++r)
        part[(size_t)kc * 524288 + (size_t)(mbase + r) * 128 + nt * 16 + ln] = acc[st][nt][r];
  }
}

// ---------------------------------------------------------------------------
// reduce K-split partials; write gi3h slot 6 (emb fp16) + embbf (bf16 pairs)
__global__ void k_emb_reduce(const float* __restrict__ part, const float* __restrict__ b_emb,
                             _Float16* __restrict__ gih, unsigned* __restrict__ embbf) {
  const unsigned pidx = blockIdx.x * 256u + threadIdx.x;  // < 262144 pairs
  const unsigned e0 = (pidx * 2u) & 127u;
  const unsigned m = pidx >> 6;  // row (t*64+b)
  float2 s = ((const float2*)b_emb)[e0 >> 1];
#pragma unroll
  for (int kc = 0; kc < 8; ++kc) {
    float2 v = ((const float2*)(part + (size_t)kc * 524288u))[pidx];
    s.x += v.x; s.y += v.y;
  }
  gih[(size_t)m * 1024u + e0 * 8u + 6u] = (_Float16)s.x;
  gih[(size_t)m * 1024u + (e0 + 1u) * 8u + 6u] = (_Float16)s.y;
  embbf[pidx] = pkbf(s.x, s.y);
}

// ---------------------------------------------------------------------------
// gi3h gates: col g: gate gg=g>>7 (0..2: GRU-a r,z,n; 3..5: b), kout=g&127 ->
// gih[row*1024 + kout*8 + gg] (fp16). b_ih always folded; b_hh folded for r,z.
__global__ __launch_bounds__(256) void k_gi_gemm(const unsigned short* __restrict__ embbf,
                                                 const unsigned short* __restrict__ wih,
                                                 const float* __restrict__ b_ih_a,
                                                 const float* __restrict__ b_ih_b,
                                                 const float* __restrict__ b_hh_a,
                                                 const float* __restrict__ b_hh_b,
                                                 _Float16* __restrict__ gih) {
  const int mt = blockIdx.x / 6, nt6 = blockIdx.x % 6, nbase = nt6 * 128;
  const int w = threadIdx.x >> 6, lane = threadIdx.x & 63, q = lane >> 4, ln = lane & 15;
  const f32x4 zero = {0.f, 0.f, 0.f, 0.f};
  f32x4 acc[2][8];
#pragma unroll
  for (int a = 0; a < 2; ++a)
#pragma unroll
    for (int b = 0; b < 8; ++b) acc[a][b] = zero;

#pragma unroll
  for (int kk = 0; kk < 4; ++kk) {
    const int ko = kk * 32 + q * 8;
    short8 a0 = *(const short8*)(embbf + (size_t)(mt * 128 + (2 * w) * 16 + ln) * 128 + ko);
    short8 a1 = *(const short8*)(embbf + (size_t)(mt * 128 + (2 * w + 1) * 16 + ln) * 128 + ko);
#pragma unroll
    for (int nt = 0; nt < 8; ++nt) {
      short8 b = *(const short8*)(wih + (size_t)(nbase + nt * 16 + ln) * 128 + ko);
      acc[0][nt] = MFMA16(a0, b, acc[0][nt]);
      acc[1][nt] = MFMA16(a1, b, acc[1][nt]);
    }
  }
#pragma unroll
  for (int nt = 0; nt < 8; ++nt) {
    const int g = nbase + nt * 16 + ln;
    const int gg = g >> 7, kout = g & 127;
    float bias;
    if (g < 384) bias = b_ih_a[g] + ((gg < 2) ? b_hh_a[g] : 0.0f);
    else {
      const int g2 = g - 384;
      bias = b_ih_b[g2] + ((gg < 5) ? b_hh_b[g2] : 0.0f);
    }
#pragma unroll
    for (int st = 0; st < 2; ++st) {
      const int mbase = mt * 128 + (2 * w + st) * 16 + q * 4;
#pragma unroll
      for (int r = 0; r < 4; ++r)
        gih[(size_t)(mbase + r) * 1024 + kout * 8 + gg] = (_Float16)(acc[st][nt][r] + bias);
    }
  }
}

// ---------------------------------------------------------------------------
// Fused recurrence + attention, deferred by one step. 256 blocks x 512 thr.
// Per iteration s: read h_s frags ONCE -> gate MFMAs (h_{s+1}) + beta(h_s) +
// logit(h_s) (finalizes term s-1). One raw barrier (lgkmcnt drain only) so
// the next-step gi prefetch stays in flight across it.
__global__ __launch_bounds__(512) __attribute__((amdgpu_waves_per_eu(2, 2)))
void k_recur(const _Float16* __restrict__ gih,
             const unsigned short* __restrict__ whha, const unsigned short* __restrict__ whhb,
             const unsigned short* __restrict__ wbeta,
             const float* __restrict__ b_hh_a, const float* __restrict__ b_hh_b,
             const float* __restrict__ b_beta, const float* __restrict__ b_alpha,
             const float* __restrict__ w_alpha,
             unsigned short* __restrict__ cbf) {
  const int tid = threadIdx.x, w = tid >> 6, lane = tid & 63, q = lane >> 4, ln = lane & 15;
  const int p = blockIdx.x >> 3, btile = blockIdx.x & 7;
  const int i1 = p, i2 = 63 - p;  // i2 >= i1
  const int kout = w * 16 + ln;

  __shared__ unsigned short hA[2][16 * 136], hB[2][16 * 136];
  __shared__ unsigned short wbeta_s[16384];  // fragment order (R4 fix)

  for (int idx = tid; idx < 16 * 136; idx += 512) { hA[0][idx] = 0; hB[0][idx] = 0; }
  for (int c = tid; c < 2048; c += 512) {
    const int cw = c >> 8, ckc = (c >> 6) & 3, cq = (c >> 4) & 3, cl = c & 15;
    *(short8*)(wbeta_s + c * 8) =
        *(const short8*)(wbeta + (size_t)(cw * 16 + cl) * 128 + ckc * 32 + cq * 8);
  }

  const int iq = (q < 2) ? i1 : i2;
  const _Float16* gp[4];
#pragma unroll
  for (int r = 0; r < 4; ++r) {
    const int b = btile * 8 + (q & 1) * 4 + r;
    gp[r] = gih + (size_t)(iq * 64 + b) * 1024 + kout * 8;
  }

  // ---- W_hh B-fragments -> AGPRs (96 regs, pinned)
  short8 fra[3][4], frb[3][4];
#pragma unroll
  for (int g = 0; g < 3; ++g) {
    const unsigned short* ba = whha + (size_t)(g * 128 + kout) * 128;
    const unsigned short* bb = whhb + (size_t)(g * 128 + kout) * 128;
#pragma unroll
    for (int kc = 0; kc < 4; ++kc) {
      fra[g][kc] = *(const short8*)(ba + kc * 32 + q * 8);
      frb[g][kc] = *(const short8*)(bb + kc * 32 + q * 8);
    }
  }
#pragma unroll
  for (int g = 0; g < 3; ++g)
#pragma unroll
    for (int kc = 0; kc < 4; ++kc) {
      asm volatile("" : "+a"(fra[g][kc]));
      asm volatile("" : "+a"(frb[g][kc]));
    }

  // ---- alpha B-fragment: col 0 = 0.5*w_alpha, cols 1..15 = 0 (AGPR, 16 regs)
  short8 fal[4];
#pragma unroll
  for (int kc = 0; kc < 4; ++kc) {
    float4 w0 = *(const float4*)(w_alpha + kc * 32 + q * 8);
    float4 w1 = *(const float4*)(w_alpha + kc * 32 + q * 8 + 4);
    union { short8 v; unsigned u[4]; } t;
    t.u[0] = pkbf(0.5f * w0.x, 0.5f * w0.y); t.u[1] = pkbf(0.5f * w0.z, 0.5f * w0.w);
    t.u[2] = pkbf(0.5f * w1.x, 0.5f * w1.y); t.u[3] = pkbf(0.5f * w1.z, 0.5f * w1.w);
    const short8 z8 = {0, 0, 0, 0, 0, 0, 0, 0};
    fal[kc] = (ln == 0) ? t.v : z8;
    asm volatile("" : "+a"(fal[kc]));
  }

  const float bhnA = b_hh_a[256 + kout];
  const float bhnB = b_hh_b[256 + kout];
  const float bbet = b_beta[kout];
  const float bal = b_alpha[0];

  float hRA[4], hRB[4], cac[4], lreg[4], embp[4];
#pragma unroll
  for (int r = 0; r < 4; ++r) { hRA[r] = 0.f; hRB[r] = 0.f; cac[r] = 0.f; lreg[r] = 0.f; embp[r] = 0.f; }

  const f32x4 zero = {0.f, 0.f, 0.f, 0.f};
  int jj = iq;
  half8 ngv[4];
#pragma unroll
  for (int r = 0; r < 4; ++r) ngv[r] = *(const half8*)gp[r];

  __syncthreads();

  for (int s = 0; s <= i2; ++s) {
    const int rb = s & 1, wb = rb ^ 1;

    half8 gv[4];
#pragma unroll
    for (int r = 0; r < 4; ++r) gv[r] = ngv[r];

    // ---- h_s A-fragments (read ONCE; feed gates + beta + alpha)
    short8 haf[4], hbf[4], fbe[4];
#pragma unroll
    for (int kc = 0; kc < 4; ++kc) {
      haf[kc] = *(const short8*)(hA[rb] + ln * 136 + kc * 32 + q * 8);
      hbf[kc] = *(const short8*)(hB[rb] + ln * 136 + kc * 32 + q * 8);
      fbe[kc] = *(const short8*)(wbeta_s + (size_t)(((w * 4 + kc) * 4 + q) * 16 + ln) * 8);
    }

    // ---- MFMA clump: 24 gates + 4 beta + 4 alpha
    f32x4 accA[3] = {zero, zero, zero}, accB[3] = {zero, zero, zero};
    f32x4 accV = zero, accL = zero;
#pragma unroll
    for (int kc = 0; kc < 4; ++kc) {
#pragma unroll
      for (int g = 0; g < 3; ++g) {
        accA[g] = MFMA16(haf[kc], fra[g][kc], accA[g]);
        accB[g] = MFMA16(hbf[kc], frb[g][kc], accB[g]);
      }
      accV = MFMA16(hbf[kc], fbe[kc], accV);
      accL = MFMA16(haf[kc], fal[kc], accL);
    }

    // ---- finalize attention term s-1 (uses h_s): pp, beta, emb from s-1
    const bool act = ((unsigned)(s - 1) <= (unsigned)iq);
#pragma unroll
    for (int r = 0; r < 4; ++r) {
      const float logit = __shfl(accL[r], lane & 48) + bal;  // col0 at lane q*16
      const float pp = act ? __expf(logit) : 0.0f;
      lreg[r] += pp;
      const float beta = tanh_f(accV[r] + bbet);
      cac[r] += pp * beta * embp[r];
    }

    // ---- gate math -> h_{s+1}, write to buf wb
#pragma unroll
    for (int r = 0; r < 4; ++r) {
      const int rowoff = (q * 4 + r) * 136 + kout;
      const float rrA = sigm((float)gv[r][0] + accA[0][r]);
      const float zzA = sigm((float)gv[r][1] + accA[1][r]);
      const float nnA = tanh_f((float)gv[r][2] + rrA * (accA[2][r] + bhnA));
      const float hnA = fmaf(zzA, hRA[r] - nnA, nnA);
      hRA[r] = hnA;
      hA[wb][rowoff] = f2bf(hnA);

      const float rrB = sigm((float)gv[r][3] + accB[0][r]);
      const float zzB = sigm((float)gv[r][4] + accB[1][r]);
      const float nnB = tanh_f((float)gv[r][5] + rrB * (accB[2][r] + bhnB));
      const float hnB = fmaf(zzB, hRB[r] - nnB, nnB);
      hRB[r] = hnB;
      hB[wb][rowoff] = f2bf(hnB);

      embp[r] = (float)gv[r][6];
    }

    // ---- advance + prefetch s+1 (stays in flight across the raw barrier)
    if (jj > 0) {
      --jj;
#pragma unroll
      for (int r = 0; r < 4; ++r) gp[r] -= 65536;  // 64 rows * 1024 halves
    }
#pragma unroll
    for (int r = 0; r < 4; ++r) ngv[r] = *(const half8*)gp[r];

    // raw barrier: drain LDS only; global prefetch loads stay outstanding
    asm volatile("s_waitcnt lgkmcnt(0)\n\ts_barrier" ::: "memory");
  }

  // ---- epilogue: finalize term i2 (active only for rows with iq == i2)
  {
    const int rb2 = (i2 + 1) & 1;
    short8 haf[4], hbf[4], fbe[4];
#pragma unroll
    for (int kc = 0; kc < 4; ++kc) {
      haf[kc] = *(const short8*)(hA[rb2] + ln * 136 + kc * 32 + q * 8);
      hbf[kc] = *(const short8*)(hB[rb2] + ln * 136 + kc * 32 + q * 8);
      fbe[kc] = *(const short8*)(wbeta_s + (size_t)(((w * 4 + kc) * 4 + q) * 16 + ln) * 8);
    }
    f32x4 accV = zero, accL = zero;
#pragma unroll
    for (int kc = 0; kc < 4; ++kc) {
      accV = MFMA16(hbf[kc], fbe[kc], accV);
      accL = MFMA16(haf[kc], fal[kc], accL);
    }
    const bool act = (iq == i2);
#pragma unroll
    for (int r = 0; r < 4; ++r) {
      const float logit = __shfl(accL[r], lane & 48) + bal;
      const float pp = act ? __expf(logit) : 0.0f;
      lreg[r] += pp;
      const float beta = tanh_f(accV[r] + bbet);
      cac[r] += pp * beta * embp[r];
    }
  }

#pragma unroll
  for (int r = 0; r < 4; ++r) {
    const int b = btile * 8 + (q & 1) * 4 + r;
    const float val = cac[r] / (lreg[r] * (float)(iq + 1));
    cbf[(size_t)(iq * 64 + b) * 128 + kout] = f2bf(val);
  }
}

// ---------------------------------------------------------------------------
// out = sigmoid(c @ W_out.T + b_out): M=4096, N=4096, K=128. 1024 blocks of 128x128.
__global__ __launch_bounds__(256) void k_out_gemm(const unsigned short* __restrict__ cbf,
                                                  const unsigned short* __restrict__ wout,
                                                  const float* __restrict__ b_out,
                                                  float* __restrict__ out) {
  const int mt = blockIdx.x >> 5, nt32 = blockIdx.x & 31, nbase = nt32 * 128;
  const int w = threadIdx.x >> 6, lane = threadIdx.x & 63, q = lane >> 4, ln = lane & 15;
  const f32x4 zero = {0.f, 0.f, 0.f, 0.f};
  f32x4 acc[2][8];
#pragma unroll
  for (int a = 0; a < 2; ++a)
#pragma unroll
    for (int b = 0; b < 8; ++b) acc[a][b] = zero;

#pragma unroll
  for (int kk = 0; kk < 4; ++kk) {
    const int ko = kk * 32 + q * 8;
    short8 a0 = *(const short8*)(cbf + (size_t)(mt * 128 + (2 * w) * 16 + ln) * 128 + ko);
    short8 a1 = *(const short8*)(cbf + (size_t)(mt * 128 + (2 * w + 1) * 16 + ln) * 128 + ko);
#pragma unroll
    for (int nt = 0; nt < 8; ++nt) {
      short8 b = *(const short8*)(wout + (size_t)(nbase + nt * 16 + ln) * 128 + ko);
      acc[0][nt] = MFMA16(a0, b, acc[0][nt]);
      acc[1][nt] = MFMA16(a1, b, acc[1][nt]);
    }
  }
#pragma unroll
  for (int nt = 0; nt < 8; ++nt) {
    const int n = nbase + nt * 16 + ln;
    const float bo = b_out[n];
#pragma unroll
    for (int st = 0; st < 2; ++st) {
      const int mbase = mt * 128 + (2 * w + st) * 16 + q * 4;
#pragma unroll
      for (int r = 0; r < 4; ++r)
        out[(size_t)(mbase + r) * 4096 + n] = sigm(acc[st][nt][r] + bo);
    }
  }
}

// ---------------------------------------------------------------------------
extern "C" void kernel_launch(void* const* d_in, const int* in_sizes, int n_in,
                              void* d_out, int out_size, void* d_ws, size_t ws_size,
                              hipStream_t stream) {
  const float* x      = (const float*)d_in[0];
  const float* W_emb  = (const float*)d_in[1];
  const float* b_emb  = (const float*)d_in[2];
  const float* W_ih_a = (const float*)d_in[3];
  const float* W_hh_a = (const float*)d_in[4];
  const float* b_ih_a = (const float*)d_in[5];
  const float* b_hh_a = (const float*)d_in[6];
  const float* W_ih_b = (const float*)d_in[7];
  const float* W_hh_b = (const float*)d_in[8];
  const float* b_ih_b = (const float*)d_in[9];
  const float* b_hh_b = (const float*)d_in[10];
  const float* w_alpha = (const float*)d_in[11];
  const float* b_alpha = (const float*)d_in[12];
  const float* W_beta = (const float*)d_in[13];
  const float* b_beta = (const float*)d_in[14];
  const float* W_out  = (const float*)d_in[15];
  const float* b_out  = (const float*)d_in[16];
  float* out = (float*)d_out;

  char* ws = (char*)d_ws;
  float*          part   = (float*)(ws + OFF_PART);
  _Float16*       gih    = (_Float16*)(ws + OFF_GI3);
  unsigned*       embbf  = (unsigned*)(ws + OFF_EMBBF);
  unsigned short* cbf    = (unsigned short*)(ws + OFF_CBF);
  unsigned*       wemb   = (unsigned*)(ws + OFF_WEMB);
  unsigned*       wout   = (unsigned*)(ws + OFF_WOUT);
  unsigned*       whha   = (unsigned*)(ws + OFF_WHHA);
  unsigned*       whhb   = (unsigned*)(ws + OFF_WHHB);
  unsigned*       wih    = (unsigned*)(ws + OFF_WIH);
  unsigned*       wbeta  = (unsigned*)(ws + OFF_WBETA);

  k_prep<<<1024, 256, 0, stream>>>(W_emb, W_out, W_hh_a, W_hh_b, W_ih_a, W_ih_b,
                                   W_beta, wemb, wout, whha, whhb, wih, wbeta);
  k_emb_gemm<<<256, 256, 0, stream>>>(x, (const unsigned short*)wemb, part);
  k_emb_reduce<<<1024, 256, 0, stream>>>(part, b_emb, gih, embbf);
  k_gi_gemm<<<192, 256, 0, stream>>>((const unsigned short*)embbf, (const unsigned short*)wih,
                                     b_ih_a, b_ih_b, b_hh_a, b_hh_b, gih);
  k_recur<<<256, 512, 0, stream>>>(gih, (const unsigned short*)whha,
                                   (const unsigned short*)whhb, (const unsigned short*)wbeta,
                                   b_hh_a, b_hh_b, b_beta, b_alpha, w_alpha, cbf);
  k_out_gemm<<<1024, 256, 0, stream>>>(cbf, (const unsigned short*)wout, b_out, out);
}